// Round 9
// baseline (117.219 us; speedup 1.0000x reference)
//
#include <hip/hip_runtime.h>
#include <hip/hip_bf16.h>

// QLSTM — DIAGNOSTIC ROUND: p1 launched 3x (idempotent) to split p1/p2 time.
// total = 3*p1 + p2;  p1 = (total - 69.5us)/2.
// Kernels are byte-identical to the best config (R5: 69.5us).
//
// qlayer(x,th) with c_w = cos(x_w+th_w): out = [c1c2c3, c0c1, c0c1c2, c0c1c2c3]
// Phase 1 (MFMA): sx = x·Wx via split-bf16 mfma_16x16x32; d2x exact f32.
// Phase 2: 16 lanes per batch element; intra-quad exchanges via quad_perm DPP.

#define T_STEPS 128
#define BATCH 512
#define IDIM 512

typedef __attribute__((ext_vector_type(8))) short bf16x8;
typedef __attribute__((ext_vector_type(4))) float f32x4;

static __device__ __forceinline__ short bfbits(__hip_bfloat16 h) {
    union { __hip_bfloat16 b; short s; } c; c.b = h; return c.s;
}

// quad_perm DPP: xor1 = [1,0,3,2] = 0xB1, xor2 = [2,3,0,1] = 0x4E,
// xor3 = [3,2,1,0] = 0x1B
template<int CTRL>
static __device__ __forceinline__ float qperm(float v) {
    return __int_as_float(__builtin_amdgcn_update_dpp(
        0, __float_as_int(v), CTRL, 0xF, 0xF, true));
}

// ---------------- Phase 1 ----------------
// grid 512 blocks x 512 threads (8 waves). Each wave: one 16-row tile,
// K=512 in 16 steps of 32. A-frags loaded straight from global (f32),
// converted to bf16 hi/lo in registers. W bf16 hi/lo fragments in LDS.
__global__ __launch_bounds__(512) void qlstm_p1(
    const float* __restrict__ x,
    const float* __restrict__ Wf, const float* __restrict__ Wi,
    const float* __restrict__ Wu, const float* __restrict__ Wo,
    const float* __restrict__ kv,
    float* __restrict__ ws)
{
    __shared__ __align__(16) unsigned short whi[16 * 64 * 8];  // 16 KB [ks][lane][8]
    __shared__ __align__(16) unsigned short wlo[16 * 64 * 8];  // 16 KB
    __shared__ __align__(16) float kvl[IDIM];                  // 2 KB (linear copy)

    const int tid = threadIdx.x;

    // ---- stage W as bf16 hi/lo MFMA B-fragments ----
#pragma unroll
    for (int kk = 0; kk < 2; ++kk) {
        const int idx = tid + kk * 512;    // 0..1023 = (ks, lane)
        const int ks = idx >> 6;
        const int l  = idx & 63;
        const int c  = l & 15;             // output col n = g*4+q
        const int bq = l >> 4;             // k-chunk
        const int g  = c >> 2, q = c & 3;
        const float* Wsel = (g == 0) ? Wf : (g == 1) ? Wi : (g == 2) ? Wu : Wo;
        const float* src = Wsel + (size_t)q * 516 + ks * 32 + bq * 8;
        float4 w0 = *(const float4*)src;
        float4 w1 = *(const float4*)(src + 4);
        float wf8[8] = {w0.x, w0.y, w0.z, w0.w, w1.x, w1.y, w1.z, w1.w};
        unsigned short h8[8], l8[8];
#pragma unroll
        for (int j = 0; j < 8; ++j) {
            __hip_bfloat16 h = __float2bfloat16(wf8[j]);
            h8[j] = (unsigned short)bfbits(h);
            float r = wf8[j] - __bfloat162float(h);
            l8[j] = (unsigned short)bfbits(__float2bfloat16(r));
        }
        *(uint4*)&whi[idx * 8] = *(const uint4*)h8;
        *(uint4*)&wlo[idx * 8] = *(const uint4*)l8;
    }
    if (tid < 128)
        *(float4*)&kvl[tid * 4] = *(const float4*)(kv + tid * 4);
    __syncthreads();

    const int lane  = tid & 63;
    const int wave  = tid >> 6;
    const int row16 = lane & 15;          // A row within tile
    const int kb    = lane >> 4;          // k-chunk 0..3
    const int rowbase = (blockIdx.x * 8 + wave) * 16;

    const float* xp = x + (size_t)(rowbase + row16) * IDIM + kb * 8;

    f32x4 acc = {0.f, 0.f, 0.f, 0.f};
    float d2 = 0.f;

    float4 pA[2], pB[2];
    pA[0] = *(const float4*)(xp);       pB[0] = *(const float4*)(xp + 4);
    pA[1] = *(const float4*)(xp + 32);  pB[1] = *(const float4*)(xp + 36);

#pragma unroll
    for (int ks = 0; ks < 16; ++ks) {
        const int sl = ks & 1;
        float xf[8] = {pA[sl].x, pA[sl].y, pA[sl].z, pA[sl].w,
                       pB[sl].x, pB[sl].y, pB[sl].z, pB[sl].w};
        if (ks + 2 < 16) {   // refill the slot we just drained
            pA[sl] = *(const float4*)(xp + (ks + 2) * 32);
            pB[sl] = *(const float4*)(xp + (ks + 2) * 32 + 4);
        }

        // exact-f32 distance accumulation
        const float* kvp = &kvl[ks * 32 + kb * 8];
        float4 kva = *(const float4*)kvp;
        float4 kvb = *(const float4*)(kvp + 4);
        float kvv[8] = {kva.x, kva.y, kva.z, kva.w, kvb.x, kvb.y, kvb.z, kvb.w};
#pragma unroll
        for (int j = 0; j < 8; ++j) {
            float dx = xf[j] - kvv[j];
            d2 = fmaf(dx, dx, d2);
        }

        // split bf16 A-fragments
        bf16x8 ah, al;
#pragma unroll
        for (int j = 0; j < 8; ++j) {
            __hip_bfloat16 h = __float2bfloat16(xf[j]);
            ah[j] = bfbits(h);
            float r = xf[j] - __bfloat162float(h);
            al[j] = bfbits(__float2bfloat16(r));
        }

        bf16x8 wh = *(const bf16x8*)&whi[(ks * 64 + lane) * 8];
        bf16x8 wl = *(const bf16x8*)&wlo[(ks * 64 + lane) * 8];

        acc = __builtin_amdgcn_mfma_f32_16x16x32_bf16(ah, wh, acc, 0, 0, 0);
        acc = __builtin_amdgcn_mfma_f32_16x16x32_bf16(al, wh, acc, 0, 0, 0);
        acc = __builtin_amdgcn_mfma_f32_16x16x32_bf16(ah, wl, acc, 0, 0, 0);
    }

    // reduce d2 over the 4 kb-lanes of each row (lane bits 4,5)
    d2 += __shfl_xor(d2, 16);
    d2 += __shfl_xor(d2, 32);

    // epilogue: C layout col = lane&15, row = (lane>>4)*4 + reg
    const int ccol = lane & 15;
    const int crow = (lane >> 4) * 4;
#pragma unroll
    for (int j = 0; j < 4; ++j)
        ws[(size_t)(rowbase + crow + j) * 20 + ccol] = acc[j];
    if (lane < 16)
        ws[(size_t)(rowbase + lane) * 20 + 16] = d2;
}

// ---------------- Phase 2 ----------------
// grid 128 blocks x 64 threads; 16 lanes per batch element b.
// lane s = g*4+q (g: gate f/i/u/o, q: wire). hx kept in xor-relative order.
// Intra-quad exchanges via quad_perm DPP; gate-gather via shfl_xor.
__global__ __launch_bounds__(64) void qlstm_p2(
    const float* __restrict__ ws,
    const float* __restrict__ Wf, const float* __restrict__ Wi,
    const float* __restrict__ Wu, const float* __restrict__ Wo,
    const float* __restrict__ bf, const float* __restrict__ bi,
    const float* __restrict__ bu, const float* __restrict__ bo,
    const float* __restrict__ thf, const float* __restrict__ thi,
    const float* __restrict__ thu, const float* __restrict__ tho,
    const float* __restrict__ kv,
    float* __restrict__ out)
{
    const int lane = threadIdx.x;                 // 0..63
    const int b    = blockIdx.x * 4 + (lane >> 4);
    const int s    = lane & 15;
    const int g    = s >> 2;
    const int q    = s & 3;

    const float* W  = (g == 0) ? Wf  : (g == 1) ? Wi  : (g == 2) ? Wu  : Wo;
    const float* bb = (g == 0) ? bf  : (g == 1) ? bi  : (g == 2) ? bu  : bo;
    const float* th = (g == 0) ? thf : (g == 1) ? thi : (g == 2) ? thu : tho;

    // Wh row and kv tail in xor-relative order (index k holds element q^k)
    const float wh0 = W[(size_t)q * 516 + 512 + (q ^ 0)];
    const float wh1 = W[(size_t)q * 516 + 512 + (q ^ 1)];
    const float wh2 = W[(size_t)q * 516 + 512 + (q ^ 2)];
    const float wh3 = W[(size_t)q * 516 + 512 + (q ^ 3)];
    const float bias  = bb[q];
    const float theta = th[q];
    const float kh0 = kv[512 + (q ^ 0)];
    const float kh1 = kv[512 + (q ^ 1)];
    const float kh2 = kv[512 + (q ^ 2)];
    const float kh3 = kv[512 + (q ^ 3)];

    const bool g0m = (g == 0), g1m = (g == 1), g2m = (g == 2);
    const bool q0m = (q == 0), q1m = (q == 1);
    const bool qodd = (q & 1);

    float h0 = 0.f, h1 = 0.f, h2 = 0.f, h3 = 0.f, cx = 0.f;

    float sx  = ws[(size_t)b * 20 + s];
    float d2x = ws[(size_t)b * 20 + 16];

    for (int t = 0; t < T_STEPS; ++t) {
        float sx_n = 0.f, d2_n = 0.f;
        if (t < T_STEPS - 1) {
            const size_t rn = (size_t)(t + 1) * BATCH + b;
            sx_n = ws[rn * 20 + s];
            d2_n = ws[rn * 20 + 16];
        }

        // gate scalar
        float dh0 = h0 - kh0, dh1 = h1 - kh1, dh2 = h2 - kh2, dh3 = h3 - kh3;
        float d2h = dh0 * dh0;
        d2h = fmaf(dh1, dh1, d2h);
        d2h = fmaf(dh2, dh2, d2h);
        d2h = fmaf(dh3, dh3, d2h);
        float gate = __expf(-0.001f * (d2x + d2h));

        // pre-activation for this (g,q)
        float pre = sx + bias;
        pre = fmaf(wh0, h0, pre);
        pre = fmaf(wh1, h1, pre);
        pre = fmaf(wh2, h2, pre);
        pre = fmaf(wh3, h3, pre);
        pre *= gate;

        float cang = __cosf(pre + theta);

        // cross-wire products within the gate quad — quad_perm DPP
        float s1 = qperm<0xB1>(cang);
        float s2 = qperm<0x4E>(cang);
        float s3 = qperm<0x1B>(cang);
        float m23 = s2 * s3;
        float A  = q0m ? s1 : cang;
        float T1 = qodd ? s1 : 1.f;
        float T2 = q1m ? 1.f : m23;
        float z = A * T1 * T2;

        // activation: sigmoid for f,i,o; tanh for u (g==2)
        float tin = g2m ? (z + z) : z;
        float e  = __expf(-tin);
        float sg = 1.f / (1.f + e);
        float val = g2m ? fmaf(2.f, sg, -1.f) : sg;

        // gather all four gates' values for this wire q (LDS cross-lane)
        float a4  = __shfl_xor(val, 4);
        float a8  = __shfl_xor(val, 8);
        float a12 = __shfl_xor(val, 12);
        float f_ = g0m ? val : g1m ? a4  : g2m ? a8  : a12;
        float i_ = g0m ? a4  : g1m ? val : g2m ? a12 : a8;
        float u_ = g0m ? a8  : g1m ? a12 : g2m ? val : a4;
        float o_ = g0m ? a12 : g1m ? a8  : g2m ? a4  : val;

        float cn = fmaf(f_, cx, i_ * u_);
        float e2 = __expf(-2.f * cn);
        float thc = (1.f - e2) / (1.f + e2);
        float hn = o_ * thc;
        cx = cn;

        // share hx (xor-relative order) — quad_perm DPP
        h0 = hn;
        h1 = qperm<0xB1>(hn);
        h2 = qperm<0x4E>(hn);
        h3 = qperm<0x1B>(hn);

        if (g == 0) out[(size_t)t * (BATCH * 4) + b * 4 + q] = hn;

        sx = sx_n; d2x = d2_n;
    }

    if (g == 0) {
        const size_t base = (size_t)T_STEPS * BATCH * 4;
        out[base + b * 4 + q] = h0;
        out[base + BATCH * 4 + b * 4 + q] = cx;
    }
}

extern "C" void kernel_launch(void* const* d_in, const int* in_sizes, int n_in,
                              void* d_out, int out_size, void* d_ws, size_t ws_size,
                              hipStream_t stream) {
    const float* x   = (const float*)d_in[0];
    const float* Wf  = (const float*)d_in[1];
    const float* bf  = (const float*)d_in[2];
    const float* Wi  = (const float*)d_in[3];
    const float* bi  = (const float*)d_in[4];
    const float* Wu  = (const float*)d_in[5];
    const float* bu  = (const float*)d_in[6];
    const float* Wo  = (const float*)d_in[7];
    const float* bo  = (const float*)d_in[8];
    const float* thf = (const float*)d_in[9];
    const float* thi = (const float*)d_in[10];
    const float* thu = (const float*)d_in[11];
    const float* tho = (const float*)d_in[12];
    const float* kv  = (const float*)d_in[13];
    float* out = (float*)d_out;
    float* ws  = (float*)d_ws;   // needs 65536*20*4 = 5.24 MB

    // DIAGNOSTIC: p1 three times (idempotent). total = 3*p1 + p2.
    qlstm_p1<<<512, 512, 0, stream>>>(x, Wf, Wi, Wu, Wo, kv, ws);
    qlstm_p1<<<512, 512, 0, stream>>>(x, Wf, Wi, Wu, Wo, kv, ws);
    qlstm_p1<<<512, 512, 0, stream>>>(x, Wf, Wi, Wu, Wo, kv, ws);
    qlstm_p2<<<128, 64, 0, stream>>>(ws, Wf, Wi, Wu, Wo, bf, bi, bu, bo,
                                     thf, thi, thu, tho, kv, out);
}

// Round 10
// 67.680 us; speedup vs baseline: 1.7320x; 1.7320x over previous
//
#include <hip/hip_runtime.h>
#include <hip/hip_bf16.h>

// QLSTM: quantum layer collapses to products of cosines.
// qlayer(x,th) with c_w = cos(x_w+th_w): out = [c1c2c3, c0c1, c0c1c2, c0c1c2c3]
//
// Phase 1 (MFMA, ~24us measured R8): sx = x·Wx via split-bf16 mfma_16x16x32;
//   d2x exact f32. Near HBM floor (134MB read).
// Phase 2 (was ~46us): 16 lanes per batch element; quad_perm DPP intra-quad;
//   R9: 4-deep ws prefetch ring (covers L3/cross-XCD latency at 1 wave/SIMD,
//   no TLP) + v_rcp_f32 for both divisions (IEEE div seq was ~50cyc each).

#define T_STEPS 128
#define BATCH 512
#define IDIM 512

typedef __attribute__((ext_vector_type(8))) short bf16x8;
typedef __attribute__((ext_vector_type(4))) float f32x4;

static __device__ __forceinline__ short bfbits(__hip_bfloat16 h) {
    union { __hip_bfloat16 b; short s; } c; c.b = h; return c.s;
}

// quad_perm DPP: xor1 = [1,0,3,2] = 0xB1, xor2 = [2,3,0,1] = 0x4E,
// xor3 = [3,2,1,0] = 0x1B
template<int CTRL>
static __device__ __forceinline__ float qperm(float v) {
    return __int_as_float(__builtin_amdgcn_update_dpp(
        0, __float_as_int(v), CTRL, 0xF, 0xF, true));
}

static __device__ __forceinline__ float frcp(float v) {
    return __builtin_amdgcn_rcpf(v);
}

// ---------------- Phase 1 ----------------
// grid 512 blocks x 512 threads (8 waves). Each wave: one 16-row tile,
// K=512 in 16 steps of 32. A-frags loaded straight from global (f32),
// converted to bf16 hi/lo in registers. W bf16 hi/lo fragments in LDS.
__global__ __launch_bounds__(512) void qlstm_p1(
    const float* __restrict__ x,
    const float* __restrict__ Wf, const float* __restrict__ Wi,
    const float* __restrict__ Wu, const float* __restrict__ Wo,
    const float* __restrict__ kv,
    float* __restrict__ ws)
{
    __shared__ __align__(16) unsigned short whi[16 * 64 * 8];  // 16 KB [ks][lane][8]
    __shared__ __align__(16) unsigned short wlo[16 * 64 * 8];  // 16 KB
    __shared__ __align__(16) float kvl[IDIM];                  // 2 KB (linear copy)

    const int tid = threadIdx.x;

    // ---- stage W as bf16 hi/lo MFMA B-fragments ----
#pragma unroll
    for (int kk = 0; kk < 2; ++kk) {
        const int idx = tid + kk * 512;    // 0..1023 = (ks, lane)
        const int ks = idx >> 6;
        const int l  = idx & 63;
        const int c  = l & 15;             // output col n = g*4+q
        const int bq = l >> 4;             // k-chunk
        const int g  = c >> 2, q = c & 3;
        const float* Wsel = (g == 0) ? Wf : (g == 1) ? Wi : (g == 2) ? Wu : Wo;
        const float* src = Wsel + (size_t)q * 516 + ks * 32 + bq * 8;
        float4 w0 = *(const float4*)src;
        float4 w1 = *(const float4*)(src + 4);
        float wf8[8] = {w0.x, w0.y, w0.z, w0.w, w1.x, w1.y, w1.z, w1.w};
        unsigned short h8[8], l8[8];
#pragma unroll
        for (int j = 0; j < 8; ++j) {
            __hip_bfloat16 h = __float2bfloat16(wf8[j]);
            h8[j] = (unsigned short)bfbits(h);
            float r = wf8[j] - __bfloat162float(h);
            l8[j] = (unsigned short)bfbits(__float2bfloat16(r));
        }
        *(uint4*)&whi[idx * 8] = *(const uint4*)h8;
        *(uint4*)&wlo[idx * 8] = *(const uint4*)l8;
    }
    if (tid < 128)
        *(float4*)&kvl[tid * 4] = *(const float4*)(kv + tid * 4);
    __syncthreads();

    const int lane  = tid & 63;
    const int wave  = tid >> 6;
    const int row16 = lane & 15;          // A row within tile
    const int kb    = lane >> 4;          // k-chunk 0..3
    const int rowbase = (blockIdx.x * 8 + wave) * 16;

    const float* xp = x + (size_t)(rowbase + row16) * IDIM + kb * 8;

    f32x4 acc = {0.f, 0.f, 0.f, 0.f};
    float d2 = 0.f;

    float4 pA[2], pB[2];
    pA[0] = *(const float4*)(xp);       pB[0] = *(const float4*)(xp + 4);
    pA[1] = *(const float4*)(xp + 32);  pB[1] = *(const float4*)(xp + 36);

#pragma unroll
    for (int ks = 0; ks < 16; ++ks) {
        const int sl = ks & 1;
        float xf[8] = {pA[sl].x, pA[sl].y, pA[sl].z, pA[sl].w,
                       pB[sl].x, pB[sl].y, pB[sl].z, pB[sl].w};
        if (ks + 2 < 16) {   // refill the slot we just drained
            pA[sl] = *(const float4*)(xp + (ks + 2) * 32);
            pB[sl] = *(const float4*)(xp + (ks + 2) * 32 + 4);
        }

        // exact-f32 distance accumulation
        const float* kvp = &kvl[ks * 32 + kb * 8];
        float4 kva = *(const float4*)kvp;
        float4 kvb = *(const float4*)(kvp + 4);
        float kvv[8] = {kva.x, kva.y, kva.z, kva.w, kvb.x, kvb.y, kvb.z, kvb.w};
#pragma unroll
        for (int j = 0; j < 8; ++j) {
            float dx = xf[j] - kvv[j];
            d2 = fmaf(dx, dx, d2);
        }

        // split bf16 A-fragments
        bf16x8 ah, al;
#pragma unroll
        for (int j = 0; j < 8; ++j) {
            __hip_bfloat16 h = __float2bfloat16(xf[j]);
            ah[j] = bfbits(h);
            float r = xf[j] - __bfloat162float(h);
            al[j] = bfbits(__float2bfloat16(r));
        }

        bf16x8 wh = *(const bf16x8*)&whi[(ks * 64 + lane) * 8];
        bf16x8 wl = *(const bf16x8*)&wlo[(ks * 64 + lane) * 8];

        acc = __builtin_amdgcn_mfma_f32_16x16x32_bf16(ah, wh, acc, 0, 0, 0);
        acc = __builtin_amdgcn_mfma_f32_16x16x32_bf16(al, wh, acc, 0, 0, 0);
        acc = __builtin_amdgcn_mfma_f32_16x16x32_bf16(ah, wl, acc, 0, 0, 0);
    }

    // reduce d2 over the 4 kb-lanes of each row (lane bits 4,5)
    d2 += __shfl_xor(d2, 16);
    d2 += __shfl_xor(d2, 32);

    // epilogue: C layout col = lane&15, row = (lane>>4)*4 + reg
    const int ccol = lane & 15;
    const int crow = (lane >> 4) * 4;
#pragma unroll
    for (int j = 0; j < 4; ++j)
        ws[(size_t)(rowbase + crow + j) * 20 + ccol] = acc[j];
    if (lane < 16)
        ws[(size_t)(rowbase + lane) * 20 + 16] = d2;
}

// ---------------- Phase 2 ----------------
// grid 128 blocks x 64 threads; 16 lanes per batch element b.
// lane s = g*4+q (g: gate f/i/u/o, q: wire). hx kept in xor-relative order.
// 4-deep ws prefetch ring; intra-quad via quad_perm DPP; gather via shfl_xor;
// reciprocals via v_rcp_f32.
__global__ __launch_bounds__(64) void qlstm_p2(
    const float* __restrict__ ws,
    const float* __restrict__ Wf, const float* __restrict__ Wi,
    const float* __restrict__ Wu, const float* __restrict__ Wo,
    const float* __restrict__ bf, const float* __restrict__ bi,
    const float* __restrict__ bu, const float* __restrict__ bo,
    const float* __restrict__ thf, const float* __restrict__ thi,
    const float* __restrict__ thu, const float* __restrict__ tho,
    const float* __restrict__ kv,
    float* __restrict__ out)
{
    const int lane = threadIdx.x;                 // 0..63
    const int b    = blockIdx.x * 4 + (lane >> 4);
    const int s    = lane & 15;
    const int g    = s >> 2;
    const int q    = s & 3;

    const float* W  = (g == 0) ? Wf  : (g == 1) ? Wi  : (g == 2) ? Wu  : Wo;
    const float* bb = (g == 0) ? bf  : (g == 1) ? bi  : (g == 2) ? bu  : bo;
    const float* th = (g == 0) ? thf : (g == 1) ? thi : (g == 2) ? thu : tho;

    // Wh row and kv tail in xor-relative order (index k holds element q^k)
    const float wh0 = W[(size_t)q * 516 + 512 + (q ^ 0)];
    const float wh1 = W[(size_t)q * 516 + 512 + (q ^ 1)];
    const float wh2 = W[(size_t)q * 516 + 512 + (q ^ 2)];
    const float wh3 = W[(size_t)q * 516 + 512 + (q ^ 3)];
    const float bias  = bb[q];
    const float theta = th[q];
    const float kh0 = kv[512 + (q ^ 0)];
    const float kh1 = kv[512 + (q ^ 1)];
    const float kh2 = kv[512 + (q ^ 2)];
    const float kh3 = kv[512 + (q ^ 3)];

    const bool g0m = (g == 0), g1m = (g == 1), g2m = (g == 2);
    const bool q0m = (q == 0), q1m = (q == 1);
    const bool qodd = (q & 1);

    float h0 = 0.f, h1 = 0.f, h2 = 0.f, h3 = 0.f, cx = 0.f;

    // per-lane ws addresses: sx at +s, d2 at +16 (broadcast within the 16)
    #define WS_SX(t) ws[((size_t)(t) * BATCH + b) * 20 + s]
    #define WS_D2(t) ws[((size_t)(t) * BATCH + b) * 20 + 16]

    // prefetch ring: slots for steps t .. t+3
    float cs0 = WS_SX(0), cd0 = WS_D2(0);
    float cs1 = WS_SX(1), cd1 = WS_D2(1);
    float cs2 = WS_SX(2), cd2 = WS_D2(2);
    float cs3 = WS_SX(3), cd3 = WS_D2(3);

    #define STEP(SX, D2X, t) do {                                          \
        float dh0 = h0 - kh0, dh1 = h1 - kh1, dh2 = h2 - kh2, dh3 = h3 - kh3; \
        float d2h = fmaf(dh0, dh0, dh1 * dh1) + fmaf(dh2, dh2, dh3 * dh3); \
        float gate = __expf(-0.001f * ((D2X) + d2h));                      \
        float pre = (SX) + bias;                                           \
        pre = fmaf(wh0, h0, pre);                                          \
        pre = fmaf(wh1, h1, pre);                                          \
        pre = fmaf(wh2, h2, pre);                                          \
        pre = fmaf(wh3, h3, pre);                                          \
        float cang = __cosf(fmaf(pre, gate, theta));                       \
        float s1 = qperm<0xB1>(cang);                                      \
        float s2 = qperm<0x4E>(cang);                                      \
        float s3 = qperm<0x1B>(cang);                                      \
        float m23 = s2 * s3;                                               \
        float A  = q0m ? s1 : cang;                                        \
        float T1 = qodd ? s1 : 1.f;                                        \
        float T2 = q1m ? 1.f : m23;                                        \
        float z = A * T1 * T2;                                             \
        float tin = g2m ? (z + z) : z;                                     \
        float e  = __expf(-tin);                                           \
        float sg = frcp(1.f + e);                                          \
        float val = g2m ? fmaf(2.f, sg, -1.f) : sg;                        \
        float a4  = __shfl_xor(val, 4);                                    \
        float a8  = __shfl_xor(val, 8);                                    \
        float a12 = __shfl_xor(val, 12);                                   \
        float f_ = g0m ? val : g1m ? a4  : g2m ? a8  : a12;                \
        float i_ = g0m ? a4  : g1m ? val : g2m ? a12 : a8;                 \
        float u_ = g0m ? a8  : g1m ? a12 : g2m ? val : a4;                 \
        float o_ = g0m ? a12 : g1m ? a8  : g2m ? a4  : val;                \
        float cn = fmaf(f_, cx, i_ * u_);                                  \
        float e2 = __expf(-2.f * cn);                                      \
        float thc = (1.f - e2) * frcp(1.f + e2);                           \
        float hn = o_ * thc;                                               \
        cx = cn;                                                           \
        h0 = hn;                                                           \
        h1 = qperm<0xB1>(hn);                                              \
        h2 = qperm<0x4E>(hn);                                              \
        h3 = qperm<0x1B>(hn);                                              \
        if (g == 0) out[(size_t)(t) * (BATCH * 4) + b * 4 + q] = hn;       \
    } while (0)

    for (int tb = 0; tb < T_STEPS / 4; ++tb) {
        const int t0 = tb * 4;
        float ns0 = 0.f, nd0 = 0.f, ns1 = 0.f, nd1 = 0.f;
        float ns2 = 0.f, nd2 = 0.f, ns3 = 0.f, nd3 = 0.f;
        if (tb < T_STEPS / 4 - 1) {       // issue next 4 steps' loads NOW
            ns0 = WS_SX(t0 + 4); nd0 = WS_D2(t0 + 4);
            ns1 = WS_SX(t0 + 5); nd1 = WS_D2(t0 + 5);
            ns2 = WS_SX(t0 + 6); nd2 = WS_D2(t0 + 6);
            ns3 = WS_SX(t0 + 7); nd3 = WS_D2(t0 + 7);
        }
        STEP(cs0, cd0, t0 + 0);
        STEP(cs1, cd1, t0 + 1);
        STEP(cs2, cd2, t0 + 2);
        STEP(cs3, cd3, t0 + 3);
        cs0 = ns0; cd0 = nd0; cs1 = ns1; cd1 = nd1;
        cs2 = ns2; cd2 = nd2; cs3 = ns3; cd3 = nd3;
    }

    #undef STEP
    #undef WS_SX
    #undef WS_D2

    if (g == 0) {
        const size_t base = (size_t)T_STEPS * BATCH * 4;
        out[base + b * 4 + q] = h0;
        out[base + BATCH * 4 + b * 4 + q] = cx;
    }
}

extern "C" void kernel_launch(void* const* d_in, const int* in_sizes, int n_in,
                              void* d_out, int out_size, void* d_ws, size_t ws_size,
                              hipStream_t stream) {
    const float* x   = (const float*)d_in[0];
    const float* Wf  = (const float*)d_in[1];
    const float* bf  = (const float*)d_in[2];
    const float* Wi  = (const float*)d_in[3];
    const float* bi  = (const float*)d_in[4];
    const float* Wu  = (const float*)d_in[5];
    const float* bu  = (const float*)d_in[6];
    const float* Wo  = (const float*)d_in[7];
    const float* bo  = (const float*)d_in[8];
    const float* thf = (const float*)d_in[9];
    const float* thi = (const float*)d_in[10];
    const float* thu = (const float*)d_in[11];
    const float* tho = (const float*)d_in[12];
    const float* kv  = (const float*)d_in[13];
    float* out = (float*)d_out;
    float* ws  = (float*)d_ws;   // needs 65536*20*4 = 5.24 MB

    qlstm_p1<<<512, 512, 0, stream>>>(x, Wf, Wi, Wu, Wo, kv, ws);
    qlstm_p2<<<128, 64, 0, stream>>>(ws, Wf, Wi, Wu, Wo, bf, bi, bu, bo,
                                     thf, thi, thu, tho, kv, out);
}

// Round 11
// 64.144 us; speedup vs baseline: 1.8274x; 1.0551x over previous
//
#include <hip/hip_runtime.h>
#include <hip/hip_bf16.h>

// QLSTM: quantum layer collapses to products of cosines.
// qlayer(x,th) with c_w = cos(x_w+th_w): out = [c1c2c3, c0c1, c0c1c2, c0c1c2c3]
//
// Phase 1 (MFMA, ~24us measured R8): sx = x·Wx via split-bf16 mfma_16x16x32;
//   d2x exact f32. Near HBM floor (134MB read).
// Phase 2 (~44us): latency-bound recurrence, 16 lanes per batch element.
//   R10: gate-gather via DPP row_ror:4/8/12 (VALU latency) instead of
//   shfl_xor/ds_bpermute (LDS-pipe, ~120+cyc at 1 wave/SIMD, 3x per step).

#define T_STEPS 128
#define BATCH 512
#define IDIM 512

typedef __attribute__((ext_vector_type(8))) short bf16x8;
typedef __attribute__((ext_vector_type(4))) float f32x4;

static __device__ __forceinline__ short bfbits(__hip_bfloat16 h) {
    union { __hip_bfloat16 b; short s; } c; c.b = h; return c.s;
}

// DPP helpers. quad_perm: xor1=0xB1, xor2=0x4E, xor3=0x1B.
// row_ror:n = 0x120|n : lane i <- lane (i-n)&15 within each 16-lane row.
template<int CTRL>
static __device__ __forceinline__ float qperm(float v) {
    return __int_as_float(__builtin_amdgcn_update_dpp(
        0, __float_as_int(v), CTRL, 0xF, 0xF, true));
}

static __device__ __forceinline__ float frcp(float v) {
    return __builtin_amdgcn_rcpf(v);
}

// ---------------- Phase 1 ----------------
// grid 512 blocks x 512 threads (8 waves). Each wave: one 16-row tile,
// K=512 in 16 steps of 32. A-frags loaded straight from global (f32),
// converted to bf16 hi/lo in registers. W bf16 hi/lo fragments in LDS.
__global__ __launch_bounds__(512) void qlstm_p1(
    const float* __restrict__ x,
    const float* __restrict__ Wf, const float* __restrict__ Wi,
    const float* __restrict__ Wu, const float* __restrict__ Wo,
    const float* __restrict__ kv,
    float* __restrict__ ws)
{
    __shared__ __align__(16) unsigned short whi[16 * 64 * 8];  // 16 KB [ks][lane][8]
    __shared__ __align__(16) unsigned short wlo[16 * 64 * 8];  // 16 KB
    __shared__ __align__(16) float kvl[IDIM];                  // 2 KB (linear copy)

    const int tid = threadIdx.x;

    // ---- stage W as bf16 hi/lo MFMA B-fragments ----
#pragma unroll
    for (int kk = 0; kk < 2; ++kk) {
        const int idx = tid + kk * 512;    // 0..1023 = (ks, lane)
        const int ks = idx >> 6;
        const int l  = idx & 63;
        const int c  = l & 15;             // output col n = g*4+q
        const int bq = l >> 4;             // k-chunk
        const int g  = c >> 2, q = c & 3;
        const float* Wsel = (g == 0) ? Wf : (g == 1) ? Wi : (g == 2) ? Wu : Wo;
        const float* src = Wsel + (size_t)q * 516 + ks * 32 + bq * 8;
        float4 w0 = *(const float4*)src;
        float4 w1 = *(const float4*)(src + 4);
        float wf8[8] = {w0.x, w0.y, w0.z, w0.w, w1.x, w1.y, w1.z, w1.w};
        unsigned short h8[8], l8[8];
#pragma unroll
        for (int j = 0; j < 8; ++j) {
            __hip_bfloat16 h = __float2bfloat16(wf8[j]);
            h8[j] = (unsigned short)bfbits(h);
            float r = wf8[j] - __bfloat162float(h);
            l8[j] = (unsigned short)bfbits(__float2bfloat16(r));
        }
        *(uint4*)&whi[idx * 8] = *(const uint4*)h8;
        *(uint4*)&wlo[idx * 8] = *(const uint4*)l8;
    }
    if (tid < 128)
        *(float4*)&kvl[tid * 4] = *(const float4*)(kv + tid * 4);
    __syncthreads();

    const int lane  = tid & 63;
    const int wave  = tid >> 6;
    const int row16 = lane & 15;          // A row within tile
    const int kb    = lane >> 4;          // k-chunk 0..3
    const int rowbase = (blockIdx.x * 8 + wave) * 16;

    const float* xp = x + (size_t)(rowbase + row16) * IDIM + kb * 8;

    f32x4 acc = {0.f, 0.f, 0.f, 0.f};
    float d2 = 0.f;

    float4 pA[2], pB[2];
    pA[0] = *(const float4*)(xp);       pB[0] = *(const float4*)(xp + 4);
    pA[1] = *(const float4*)(xp + 32);  pB[1] = *(const float4*)(xp + 36);

#pragma unroll
    for (int ks = 0; ks < 16; ++ks) {
        const int sl = ks & 1;
        float xf[8] = {pA[sl].x, pA[sl].y, pA[sl].z, pA[sl].w,
                       pB[sl].x, pB[sl].y, pB[sl].z, pB[sl].w};
        if (ks + 2 < 16) {   // refill the slot we just drained
            pA[sl] = *(const float4*)(xp + (ks + 2) * 32);
            pB[sl] = *(const float4*)(xp + (ks + 2) * 32 + 4);
        }

        // exact-f32 distance accumulation
        const float* kvp = &kvl[ks * 32 + kb * 8];
        float4 kva = *(const float4*)kvp;
        float4 kvb = *(const float4*)(kvp + 4);
        float kvv[8] = {kva.x, kva.y, kva.z, kva.w, kvb.x, kvb.y, kvb.z, kvb.w};
#pragma unroll
        for (int j = 0; j < 8; ++j) {
            float dx = xf[j] - kvv[j];
            d2 = fmaf(dx, dx, d2);
        }

        // split bf16 A-fragments
        bf16x8 ah, al;
#pragma unroll
        for (int j = 0; j < 8; ++j) {
            __hip_bfloat16 h = __float2bfloat16(xf[j]);
            ah[j] = bfbits(h);
            float r = xf[j] - __bfloat162float(h);
            al[j] = bfbits(__float2bfloat16(r));
        }

        bf16x8 wh = *(const bf16x8*)&whi[(ks * 64 + lane) * 8];
        bf16x8 wl = *(const bf16x8*)&wlo[(ks * 64 + lane) * 8];

        acc = __builtin_amdgcn_mfma_f32_16x16x32_bf16(ah, wh, acc, 0, 0, 0);
        acc = __builtin_amdgcn_mfma_f32_16x16x32_bf16(al, wh, acc, 0, 0, 0);
        acc = __builtin_amdgcn_mfma_f32_16x16x32_bf16(ah, wl, acc, 0, 0, 0);
    }

    // reduce d2 over the 4 kb-lanes of each row (lane bits 4,5)
    d2 += __shfl_xor(d2, 16);
    d2 += __shfl_xor(d2, 32);

    // epilogue: C layout col = lane&15, row = (lane>>4)*4 + reg
    const int ccol = lane & 15;
    const int crow = (lane >> 4) * 4;
#pragma unroll
    for (int j = 0; j < 4; ++j)
        ws[(size_t)(rowbase + crow + j) * 20 + ccol] = acc[j];
    if (lane < 16)
        ws[(size_t)(rowbase + lane) * 20 + 16] = d2;
}

// ---------------- Phase 2 ----------------
// grid 128 blocks x 64 threads; 16 lanes per batch element b.
// lane s = g*4+q (g: gate f/i/u/o, q: wire). hx kept in xor-relative order.
// 4-deep ws prefetch ring; ALL cross-lane via DPP (quad_perm + row_ror);
// reciprocals via v_rcp_f32.
__global__ __launch_bounds__(64) void qlstm_p2(
    const float* __restrict__ ws,
    const float* __restrict__ Wf, const float* __restrict__ Wi,
    const float* __restrict__ Wu, const float* __restrict__ Wo,
    const float* __restrict__ bf, const float* __restrict__ bi,
    const float* __restrict__ bu, const float* __restrict__ bo,
    const float* __restrict__ thf, const float* __restrict__ thi,
    const float* __restrict__ thu, const float* __restrict__ tho,
    const float* __restrict__ kv,
    float* __restrict__ out)
{
    const int lane = threadIdx.x;                 // 0..63
    const int b    = blockIdx.x * 4 + (lane >> 4);
    const int s    = lane & 15;
    const int g    = s >> 2;
    const int q    = s & 3;

    const float* W  = (g == 0) ? Wf  : (g == 1) ? Wi  : (g == 2) ? Wu  : Wo;
    const float* bb = (g == 0) ? bf  : (g == 1) ? bi  : (g == 2) ? bu  : bo;
    const float* th = (g == 0) ? thf : (g == 1) ? thi : (g == 2) ? thu : tho;

    // Wh row and kv tail in xor-relative order (index k holds element q^k)
    const float wh0 = W[(size_t)q * 516 + 512 + (q ^ 0)];
    const float wh1 = W[(size_t)q * 516 + 512 + (q ^ 1)];
    const float wh2 = W[(size_t)q * 516 + 512 + (q ^ 2)];
    const float wh3 = W[(size_t)q * 516 + 512 + (q ^ 3)];
    const float bias  = bb[q];
    const float theta = th[q];
    const float kh0 = kv[512 + (q ^ 0)];
    const float kh1 = kv[512 + (q ^ 1)];
    const float kh2 = kv[512 + (q ^ 2)];
    const float kh3 = kv[512 + (q ^ 3)];

    const bool g0m = (g == 0), g1m = (g == 1), g2m = (g == 2);
    const bool q0m = (q == 0), q1m = (q == 1);
    const bool qodd = (q & 1);

    float h0 = 0.f, h1 = 0.f, h2 = 0.f, h3 = 0.f, cx = 0.f;

    // per-lane ws addresses: sx at +s, d2 at +16 (broadcast within the 16)
    #define WS_SX(t) ws[((size_t)(t) * BATCH + b) * 20 + s]
    #define WS_D2(t) ws[((size_t)(t) * BATCH + b) * 20 + 16]

    // prefetch ring: slots for steps t .. t+3
    float cs0 = WS_SX(0), cd0 = WS_D2(0);
    float cs1 = WS_SX(1), cd1 = WS_D2(1);
    float cs2 = WS_SX(2), cd2 = WS_D2(2);
    float cs3 = WS_SX(3), cd3 = WS_D2(3);

    // gate-gather via row_ror: rK delivers gate (g-K/4)&3, same wire.
    #define STEP(SX, D2X, t) do {                                          \
        float dh0 = h0 - kh0, dh1 = h1 - kh1, dh2 = h2 - kh2, dh3 = h3 - kh3; \
        float d2h = fmaf(dh0, dh0, dh1 * dh1) + fmaf(dh2, dh2, dh3 * dh3); \
        float gate = __expf(-0.001f * ((D2X) + d2h));                      \
        float pre = (SX) + bias;                                           \
        pre = fmaf(wh0, h0, pre);                                          \
        pre = fmaf(wh1, h1, pre);                                          \
        pre = fmaf(wh2, h2, pre);                                          \
        pre = fmaf(wh3, h3, pre);                                          \
        float cang = __cosf(fmaf(pre, gate, theta));                       \
        float s1 = qperm<0xB1>(cang);                                      \
        float s2 = qperm<0x4E>(cang);                                      \
        float s3 = qperm<0x1B>(cang);                                      \
        float m23 = s2 * s3;                                               \
        float A  = q0m ? s1 : cang;                                        \
        float T1 = qodd ? s1 : 1.f;                                        \
        float T2 = q1m ? 1.f : m23;                                        \
        float z = A * T1 * T2;                                             \
        float tin = g2m ? (z + z) : z;                                     \
        float e  = __expf(-tin);                                           \
        float sg = frcp(1.f + e);                                          \
        float val = g2m ? fmaf(2.f, sg, -1.f) : sg;                        \
        float r4  = qperm<0x124>(val);  /* row_ror:4  -> gate g-1 */       \
        float r8  = qperm<0x128>(val);  /* row_ror:8  -> gate g-2 */       \
        float r12 = qperm<0x12C>(val);  /* row_ror:12 -> gate g-3 */       \
        float f_ = g0m ? val : g1m ? r4  : g2m ? r8  : r12;                \
        float i_ = g0m ? r12 : g1m ? val : g2m ? r4  : r8;                 \
        float u_ = g0m ? r8  : g1m ? r12 : g2m ? val : r4;                 \
        float o_ = g0m ? r4  : g1m ? r8  : g2m ? r12 : val;                \
        float cn = fmaf(f_, cx, i_ * u_);                                  \
        float e2 = __expf(-2.f * cn);                                      \
        float thc = (1.f - e2) * frcp(1.f + e2);                           \
        float hn = o_ * thc;                                               \
        cx = cn;                                                           \
        h0 = hn;                                                           \
        h1 = qperm<0xB1>(hn);                                              \
        h2 = qperm<0x4E>(hn);                                              \
        h3 = qperm<0x1B>(hn);                                              \
        if (g == 0) out[(size_t)(t) * (BATCH * 4) + b * 4 + q] = hn;       \
    } while (0)

    for (int tb = 0; tb < T_STEPS / 4; ++tb) {
        const int t0 = tb * 4;
        float ns0 = 0.f, nd0 = 0.f, ns1 = 0.f, nd1 = 0.f;
        float ns2 = 0.f, nd2 = 0.f, ns3 = 0.f, nd3 = 0.f;
        if (tb < T_STEPS / 4 - 1) {       // issue next 4 steps' loads NOW
            ns0 = WS_SX(t0 + 4); nd0 = WS_D2(t0 + 4);
            ns1 = WS_SX(t0 + 5); nd1 = WS_D2(t0 + 5);
            ns2 = WS_SX(t0 + 6); nd2 = WS_D2(t0 + 6);
            ns3 = WS_SX(t0 + 7); nd3 = WS_D2(t0 + 7);
        }
        STEP(cs0, cd0, t0 + 0);
        STEP(cs1, cd1, t0 + 1);
        STEP(cs2, cd2, t0 + 2);
        STEP(cs3, cd3, t0 + 3);
        cs0 = ns0; cd0 = nd0; cs1 = ns1; cd1 = nd1;
        cs2 = ns2; cd2 = nd2; cs3 = ns3; cd3 = nd3;
    }

    #undef STEP
    #undef WS_SX
    #undef WS_D2

    if (g == 0) {
        const size_t base = (size_t)T_STEPS * BATCH * 4;
        out[base + b * 4 + q] = h0;
        out[base + BATCH * 4 + b * 4 + q] = cx;
    }
}

extern "C" void kernel_launch(void* const* d_in, const int* in_sizes, int n_in,
                              void* d_out, int out_size, void* d_ws, size_t ws_size,
                              hipStream_t stream) {
    const float* x   = (const float*)d_in[0];
    const float* Wf  = (const float*)d_in[1];
    const float* bf  = (const float*)d_in[2];
    const float* Wi  = (const float*)d_in[3];
    const float* bi  = (const float*)d_in[4];
    const float* Wu  = (const float*)d_in[5];
    const float* bu  = (const float*)d_in[6];
    const float* Wo  = (const float*)d_in[7];
    const float* bo  = (const float*)d_in[8];
    const float* thf = (const float*)d_in[9];
    const float* thi = (const float*)d_in[10];
    const float* thu = (const float*)d_in[11];
    const float* tho = (const float*)d_in[12];
    const float* kv  = (const float*)d_in[13];
    float* out = (float*)d_out;
    float* ws  = (float*)d_ws;   // needs 65536*20*4 = 5.24 MB

    qlstm_p1<<<512, 512, 0, stream>>>(x, Wf, Wi, Wu, Wo, kv, ws);
    qlstm_p2<<<128, 64, 0, stream>>>(ws, Wf, Wi, Wu, Wo, bf, bi, bu, bo,
                                     thf, thi, thu, tho, kv, out);
}